// Round 10
// baseline (197.670 us; speedup 1.0000x reference)
//
#include <hip/hip_runtime.h>
#include <hip/hip_bf16.h>

typedef __attribute__((ext_vector_type(8))) short short8;
typedef __attribute__((ext_vector_type(4))) float float4v;
typedef unsigned int uint;

#define NBLK 192  // blocks for hist/scatterbin passes

static __device__ __forceinline__ float2 up_bf2(uint v) {
    float2 r;
    r.x = __uint_as_float(v << 16);
    r.y = __uint_as_float(v & 0xffff0000u);
    return r;
}
static __device__ __forceinline__ short f2bf_bits(float x) {
    union { __hip_bfloat16 h; short s; } u;
    u.h = __float2bfloat16(x);
    return u.s;
}

// ---------------- per-(bucket,block) histogram, LDS only ----------------

__global__ __launch_bounds__(256) void k_hist(const int* __restrict__ dst, int E, int chunk,
        int shift, int nbuck, int* __restrict__ histBlk) {
    __shared__ int h[256];
    h[threadIdx.x] = 0;
    __syncthreads();
    int blk = blockIdx.x;
    int e0 = blk * chunk, e1 = min(E, e0 + chunk);
    for (int e = e0 + threadIdx.x; e < e1; e += 256)
        atomicAdd(&h[dst[e] >> shift], 1);
    __syncthreads();
    if (threadIdx.x < nbuck) histBlk[threadIdx.x * NBLK + blk] = h[threadIdx.x];
}

// ---------------- scatter into per-(bucket,block) slices, packed payload ----------------
// r29: bases derived INLINE from histBlk (replaces k_btot + k_bscan launches).
// Thread t computes bucket t's total and its prefix over blocks < blk from the
// L2-resident histBlk (150 KB redundant read per block, ~1-2 us total), then an
// in-LDS scan gives the global bucket base.  binned content is bit-identical
// to the 5-kernel version.  binned word = src(24b) | dst_local(8b).

__global__ __launch_bounds__(256) void k_scatterbin(const int* __restrict__ src,
        const int* __restrict__ dst, int E, int chunk, int shift, int nbuck,
        const int* __restrict__ histBlk, uint* __restrict__ binned) {
    __shared__ int cur[256], s[256];
    int blk = blockIdx.x, t = threadIdx.x;
    int total = 0, partial = 0;
    if (t < nbuck) {
        const int* row = histBlk + t * NBLK;
        for (int bl = 0; bl < NBLK; ++bl) {
            int v = row[bl];
            total += v;
            if (bl < blk) partial += v;
        }
    }
    s[t] = total;
    __syncthreads();
    for (int off = 1; off < 256; off <<= 1) {  // inclusive scan of bucket totals
        int u = (t >= off) ? s[t - off] : 0;
        __syncthreads();
        s[t] += u;
        __syncthreads();
    }
    int base = (t > 0) ? s[t - 1] : 0;         // exclusive prefix
    if (t < nbuck) cur[t] = base + partial;
    __syncthreads();
    int e0 = blk * chunk, e1 = min(E, e0 + chunk);
    int mask = (1 << shift) - 1;
    for (int e = e0 + t; e < e1; e += 256) {
        int d = dst[e];
        int pos = atomicAdd(&cur[d >> shift], 1);
        binned[pos] = (uint)src[e] | ((uint)(d & mask) << 24);
    }
}

// ---------------- per-bucket: counts -> row_ptr/dinv/xs, then exact csr scatter ----------------
// r29: lo/hi derived inline from histBlk (replaces bucketBase input).

__global__ __launch_bounds__(256) void k_csrbuild(const uint* __restrict__ binned,
        const int* __restrict__ histBlk, const float* __restrict__ x,
        int E, int shift, int n, int nbuck,
        int* __restrict__ row_ptr, float* __restrict__ dinv, float* __restrict__ xs,
        int* __restrict__ csr) {
    __shared__ int cnt[256], lcur[256];
    int b = blockIdx.x, t = threadIdx.x;
    cnt[t] = 0;
    // ---- derive lo/hi for bucket b from histBlk ----
    int total = 0;
    if (t < nbuck) {
        const int* row = histBlk + t * NBLK;
        for (int bl = 0; bl < NBLK; ++bl) total += row[bl];
    }
    lcur[t] = total;
    __syncthreads();
    for (int off = 1; off < 256; off <<= 1) {  // inclusive scan of bucket totals
        int u = (t >= off) ? lcur[t - off] : 0;
        __syncthreads();
        lcur[t] += u;
        __syncthreads();
    }
    int lo = (b > 0) ? lcur[b - 1] : 0;
    int hi = lcur[b];
    __syncthreads();   // all lo/hi reads complete before lcur is reused below
    // ---- count per-node degrees within bucket ----
    for (int e = lo + t; e < hi; e += 256)
        atomicAdd(&cnt[binned[e] >> 24], 1);
    __syncthreads();
    int c = cnt[t];
    lcur[t] = c;
    __syncthreads();
    for (int off = 1; off < 256; off <<= 1) {
        int u = (t >= off) ? lcur[t - off] : 0;
        __syncthreads();
        lcur[t] += u;
        __syncthreads();
    }
    int node0 = b << shift;
    int nodeEnd = min(n, (b + 1) << shift);
    int cntNodes = nodeEnd - node0;
    int myBase = lo + lcur[t] - c;  // exclusive prefix within bucket
    if (t < cntNodes) {
        row_ptr[node0 + t] = myBase;
        dinv[node0 + t] = rsqrtf((float)(c + 1));  // +1 self-loop
    }
    if (b == nbuck - 1 && t == 0) row_ptr[n] = E;
    for (int j = t; j < cntNodes * 9; j += 256) {
        int nl = j / 9, f = j - nl * 9;
        float dnl = rsqrtf((float)(cnt[nl] + 1));
        xs[(size_t)(node0 + nl) * 9 + f] = dnl * x[(size_t)(node0 + nl) * 9 + f];
    }
    __syncthreads();
    lcur[t] = myBase;  // running cursors
    __syncthreads();
    for (int e = lo + t; e < hi; e += 256) {
        uint p = binned[e];
        int pos = atomicAdd(&lcur[p >> 24], 1);
        csr[pos] = (int)(p & 0xFFFFFF);
    }
}

// ---------------- Layer 1 aggregate v2 (+ fused W1 frag prebuild) ----------------
// r28: 32 lanes/node = 2 edge-slots x 16 features, 8-deep unroll -> 16 edges
// per chunk, 8 gathers in flight per lane.  shfl_xor(16) merges edge slots.

__global__ __launch_bounds__(256) void k_agg1w(const float* __restrict__ xs,
                       const float* __restrict__ dinv,
                       const int* __restrict__ row_ptr, const int* __restrict__ csr,
                       const float* __restrict__ W1,
                       __hip_bfloat16* __restrict__ aggx_bf,
                       __hip_bfloat16* __restrict__ W1frag, int n, int nagg) {
    int bid = blockIdx.x;
    if (bid >= nagg) {  // W1frag role (8 blocks, 2048 threads)
        int t = (bid - nagg) * 256 + threadIdx.x;
        if (t < 32 * 64) {
            int ctile = t >> 6, lane = t & 63;
            int col = ctile * 16 + (lane & 15);
            int k0 = (lane >> 4) * 8;
            short8 o;
#pragma unroll
            for (int j = 0; j < 8; ++j) {
                int k = k0 + j;
                o[j] = f2bf_bits(k < 9 ? W1[k * 512 + col] : 0.f);
            }
            *reinterpret_cast<short8*>(W1frag + (size_t)t * 8) = o;
        }
        return;
    }
    int node = bid * 8 + (threadIdx.x >> 5);
    if (node >= n) return;
    int l = threadIdx.x & 31;
    int slot = l >> 4;        // edge slot 0/1
    int f = l & 15;
    bool act = f < 9;
    float acc = (act && slot == 0) ? xs[node * 9 + f] : 0.f;  // self-loop once
    int e0 = row_ptr[node], e1 = row_ptr[node + 1];
    int e = e0;
    for (; e + 16 <= e1; e += 16) {       // 8 gathers in flight per lane
        int si[8];
        float xv[8];
#pragma unroll
        for (int j = 0; j < 8; ++j) si[j] = csr[e + 2 * j + slot];
#pragma unroll
        for (int j = 0; j < 8; ++j) xv[j] = act ? xs[si[j] * 9 + f] : 0.f;
#pragma unroll
        for (int j = 0; j < 8; ++j) acc += xv[j];
    }
    for (; e + 4 <= e1; e += 4) {         // 2 per slot
        int s0 = csr[e + slot], s1 = csr[e + 2 + slot];
        float x0 = act ? xs[s0 * 9 + f] : 0.f;
        float x1 = act ? xs[s1 * 9 + f] : 0.f;
        acc += x0 + x1;
    }
    for (; e + 2 <= e1; e += 2) {         // 1 per slot
        int s0 = csr[e + slot];
        acc += act ? xs[s0 * 9 + f] : 0.f;
    }
    if (e < e1 && slot == 0) {            // final odd edge
        int s0 = csr[e];
        acc += act ? xs[s0 * 9 + f] : 0.f;
    }
    acc += __shfl_xor(acc, 16);           // merge edge slots
    if (slot == 0) {
        float v = act ? dinv[node] * acc : 0.f;
        __hip_bfloat16* op = aggx_bf + (size_t)node * 32;
        union { __hip_bfloat16 h; short s; } u;
        u.h = __float2bfloat16(v);
        reinterpret_cast<short*>(op)[f] = u.s;
        reinterpret_cast<short*>(op)[16 + f] = 0;
    }
}

// ---------------- Fused layer1-MFMA + layer2 GEMM (r21 best config) ----------------

__global__ __launch_bounds__(512, 2) void k_l12(const __hip_bfloat16* __restrict__ aggx_bf,
                       const __hip_bfloat16* __restrict__ W1frag, const float* __restrict__ b1,
                       const float* __restrict__ W2, const float* __restrict__ dinv,
                       __hip_bfloat16* __restrict__ t2, int n, int npair) {
    __shared__ short bsh[64 * 128 * 8];   // 128 KB: [kb 0..63][c 0..127][j 0..7]
    __shared__ short h1s[8][2][16][40];   // 20 KB: per-wave 2 tiles x 16 rows x 32 cols
    int t = threadIdx.x;

    // Stage all 128 cols of W2 (fp32 -> bf16) into LDS.
    for (int idx = t; idx < 64 * 128; idx += 512) {
        int kb = idx >> 7, c = idx & 127;
        const float* wp = W2 + (size_t)(kb * 8) * 128 + c;
        short8 o;
#pragma unroll
        for (int j = 0; j < 8; ++j) o[j] = f2bf_bits(wp[j * 128]);
        *reinterpret_cast<short8*>(bsh + (size_t)idx * 8) = o;
    }
    __syncthreads();

    int wid = t >> 6, lane = t & 63;
    int pair = blockIdx.x * 8 + wid;
    if (pair >= npair) return;
    int r = lane & 15, quad = lane >> 4;
    short (*hs0)[40] = h1s[wid][0];
    short (*hs1)[40] = h1s[wid][1];

    int m0 = pair << 5;
    short8 aagg0 = *reinterpret_cast<const short8*>(
        aggx_bf + (size_t)(m0 + r) * 32 + quad * 8);
    short8 aagg1 = *reinterpret_cast<const short8*>(
        aggx_bf + (size_t)(m0 + 16 + r) * 32 + quad * 8);

    float4v acc0[8], acc1[8];
#pragma unroll
    for (int cg = 0; cg < 8; ++cg) {
        acc0[cg] = (float4v){0, 0, 0, 0};
        acc1[cg] = (float4v){0, 0, 0, 0};
    }

    for (int kt = 0; kt < 16; ++kt) {
        short8 bf0 = *reinterpret_cast<const short8*>(
            W1frag + ((size_t)(2 * kt) * 64 + lane) * 8);
        short8 bf1 = *reinterpret_cast<const short8*>(
            W1frag + ((size_t)(2 * kt + 1) * 64 + lane) * 8);
        float4v c00 = __builtin_amdgcn_mfma_f32_16x16x32_bf16(
            aagg0, bf0, (float4v){0, 0, 0, 0}, 0, 0, 0);
        float4v c01 = __builtin_amdgcn_mfma_f32_16x16x32_bf16(
            aagg0, bf1, (float4v){0, 0, 0, 0}, 0, 0, 0);
        float4v c10 = __builtin_amdgcn_mfma_f32_16x16x32_bf16(
            aagg1, bf0, (float4v){0, 0, 0, 0}, 0, 0, 0);
        float4v c11 = __builtin_amdgcn_mfma_f32_16x16x32_bf16(
            aagg1, bf1, (float4v){0, 0, 0, 0}, 0, 0, 0);
        float bb0 = b1[kt * 32 + r];
        float bb1 = b1[kt * 32 + 16 + r];
#pragma unroll
        for (int i = 0; i < 4; ++i) {
            int row = quad * 4 + i;
            hs0[row][r]      = f2bf_bits(fmaxf(c00[i] + bb0, 0.f));
            hs0[row][16 + r] = f2bf_bits(fmaxf(c01[i] + bb1, 0.f));
            hs1[row][r]      = f2bf_bits(fmaxf(c10[i] + bb0, 0.f));
            hs1[row][16 + r] = f2bf_bits(fmaxf(c11[i] + bb1, 0.f));
        }
        short8 am0 = *reinterpret_cast<const short8*>(&hs0[r][quad * 8]);
        short8 am1 = *reinterpret_cast<const short8*>(&hs1[r][quad * 8]);
#pragma unroll
        for (int cg = 0; cg < 8; ++cg) {
            short8 b = *reinterpret_cast<const short8*>(
                bsh + (size_t)(((kt * 4 + quad) * 128) + cg * 16 + r) * 8);
            acc0[cg] = __builtin_amdgcn_mfma_f32_16x16x32_bf16(am0, b, acc0[cg], 0, 0, 0);
            acc1[cg] = __builtin_amdgcn_mfma_f32_16x16x32_bf16(am1, b, acc1[cg], 0, 0, 0);
        }
    }

#pragma unroll
    for (int i = 0; i < 4; ++i) {
        int node0 = m0 + quad * 4 + i;
        if (node0 < n) {
            float di = dinv[node0];
            __hip_bfloat16* op = t2 + (size_t)node0 * 128 + r;
#pragma unroll
            for (int cg = 0; cg < 8; ++cg)
                op[cg * 16] = __float2bfloat16(di * acc0[cg][i]);
        }
        int node1 = m0 + 16 + quad * 4 + i;
        if (node1 < n) {
            float di = dinv[node1];
            __hip_bfloat16* op = t2 + (size_t)node1 * 128 + r;
#pragma unroll
            for (int cg = 0; cg < 8; ++cg)
                op[cg * 16] = __float2bfloat16(di * acc1[cg][i]);
        }
    }
}

// ---------------- Layer 2 aggregate + fused layer-3 matmul (r20 proven) ----------------

__global__ __launch_bounds__(256) void k_agg2(const uint* __restrict__ t2u,
                       const float* __restrict__ dinv,
                       const int* __restrict__ row_ptr, const int* __restrict__ csr,
                       const float* __restrict__ b2, const float* __restrict__ W3,
                       float2* __restrict__ t3, int n) {
    int node = blockIdx.x * 4 + (threadIdx.x >> 6);
    if (node >= n) return;
    int lane = threadIdx.x & 63;
    int half = lane >> 5;    // 0: even edges, 1: odd edges
    int cl = lane & 31;      // channel chunk: channels 4*cl .. 4*cl+3
    const uint2* t2v = reinterpret_cast<const uint2*>(t2u);

    float a0 = 0.f, a1 = 0.f, a2 = 0.f, a3 = 0.f;
    if (half == 0) {  // self row (t2' = dinv*t2), added once
        uint2 sv = t2v[(size_t)node * 32 + cl];
        float2 pa = up_bf2(sv.x), pb = up_bf2(sv.y);
        a0 = pa.x; a1 = pa.y; a2 = pb.x; a3 = pb.y;
    }

    int e0 = row_ptr[node], e1 = row_ptr[node + 1];
    int eb = e0;
    for (; eb + 16 <= e1; eb += 16) {  // 8 edges per half in flight
        int si[8];
        uint2 ri[8];
#pragma unroll
        for (int j = 0; j < 8; ++j) si[j] = csr[eb + half + 2 * j];
#pragma unroll
        for (int j = 0; j < 8; ++j) ri[j] = t2v[(size_t)si[j] * 32 + cl];
#pragma unroll
        for (int j = 0; j < 8; ++j) {
            float2 qa = up_bf2(ri[j].x), qb = up_bf2(ri[j].y);
            a0 += qa.x; a1 += qa.y; a2 += qb.x; a3 += qb.y;
        }
    }
    for (; eb + 4 <= e1; eb += 4) {  // 2 edges per half
        int s0 = csr[eb + half], s1 = csr[eb + half + 2];
        uint2 r0 = t2v[(size_t)s0 * 32 + cl];
        uint2 r1 = t2v[(size_t)s1 * 32 + cl];
        float2 qa = up_bf2(r0.x), qb = up_bf2(r0.y);
        float2 qc = up_bf2(r1.x), qd = up_bf2(r1.y);
        a0 += qa.x + qc.x; a1 += qa.y + qc.y;
        a2 += qb.x + qd.x; a3 += qb.y + qd.y;
    }
    for (int e = eb + half; e < e1; e += 2) {  // tail 0-3 edges
        uint2 rv = t2v[(size_t)csr[e] * 32 + cl];
        float2 qa = up_bf2(rv.x), qb = up_bf2(rv.y);
        a0 += qa.x; a1 += qa.y; a2 += qb.x; a3 += qb.y;
    }

    // merge even/odd halves: lanes l and l^32 hold same channel chunk
    a0 += __shfl_xor(a0, 32);
    a1 += __shfl_xor(a1, 32);
    a2 += __shfl_xor(a2, 32);
    a3 += __shfl_xor(a3, 32);

    float di = dinv[node];
    float4 bb = *reinterpret_cast<const float4*>(b2 + 4 * cl);
    float h0 = fmaxf(di * a0 + bb.x, 0.f);
    float h1v = fmaxf(di * a1 + bb.y, 0.f);
    float h2 = fmaxf(di * a2 + bb.z, 0.f);
    float h3 = fmaxf(di * a3 + bb.w, 0.f);
    float4 wlo = *reinterpret_cast<const float4*>(W3 + 8 * cl);      // rows 4cl, 4cl+1
    float4 whi = *reinterpret_cast<const float4*>(W3 + 8 * cl + 4);  // rows 4cl+2, 4cl+3
    float c0 = h0 * wlo.x + h1v * wlo.z + h2 * whi.x + h3 * whi.z;
    float c1 = h0 * wlo.y + h1v * wlo.w + h2 * whi.y + h3 * whi.w;
#pragma unroll
    for (int off = 16; off; off >>= 1) {  // reduce within each 32-lane group
        c0 += __shfl_xor(c0, off);
        c1 += __shfl_xor(c1, off);
    }
    if (lane == 0) t3[node] = make_float2(di * c0, di * c1);  // prescaled
}

// ---------------- Layer 3 aggregate + log_softmax ----------------

__global__ void k_agg3(const float2* __restrict__ t3, const float* __restrict__ dinv,
                       const int* __restrict__ row_ptr, const int* __restrict__ csr,
                       const float* __restrict__ b3, float2* __restrict__ outv, int n) {
    int node = blockIdx.x * blockDim.x + threadIdx.x;
    if (node >= n) return;
    float2 s = t3[node];  // self (t3' = dinv*t3)
    float a0 = s.x, a1 = s.y;
    int e0 = row_ptr[node], e1 = row_ptr[node + 1];
    int e = e0;
    for (; e + 4 <= e1; e += 4) {
        int s0 = csr[e], s1 = csr[e + 1], s2 = csr[e + 2], s3 = csr[e + 3];
        float2 q0 = t3[s0], q1 = t3[s1], q2 = t3[s2], q3 = t3[s3];
        a0 += q0.x + q1.x + q2.x + q3.x;
        a1 += q0.y + q1.y + q2.y + q3.y;
    }
    for (; e < e1; ++e) {
        float2 q0 = t3[csr[e]];
        a0 += q0.x;
        a1 += q0.y;
    }
    float di = dinv[node];
    float z0 = di * a0 + b3[0];
    float z1 = di * a1 + b3[1];
    float m = fmaxf(z0, z1);
    float lse = m + logf(expf(z0 - m) + expf(z1 - m));
    outv[node] = make_float2(z0 - lse, z1 - lse);
}

// ---------------- launch ----------------

extern "C" void kernel_launch(void* const* d_in, const int* in_sizes, int n_in,
                              void* d_out, int out_size, void* d_ws, size_t ws_size,
                              hipStream_t stream) {
    const float* x  = (const float*)d_in[0];
    const float* W1 = (const float*)d_in[1];
    const float* b1 = (const float*)d_in[2];
    const float* W2 = (const float*)d_in[3];
    const float* b2 = (const float*)d_in[4];
    const float* W3 = (const float*)d_in[5];
    const float* b3 = (const float*)d_in[6];
    const int* edges = (const int*)d_in[7];

    int n = in_sizes[0] / 9;
    int E = in_sizes[7] / 2;
    const int* src = edges;
    const int* dst = edges + E;

    char* p = (char*)d_ws;
    auto alloc = [&](size_t bytes) {
        char* q = p;
        p += (bytes + 511) & ~(size_t)511;
        return q;
    };
    float* dinv       = (float*)alloc((size_t)n * 4);
    int*   row_ptr    = (int*)alloc((size_t)(n + 1) * 4);
    int*   csr        = (int*)alloc((size_t)E * 4);
    int*   histBlk    = (int*)alloc((size_t)256 * NBLK * 4);
    uint*  binned     = (uint*)alloc((size_t)E * 4);
    float* xs         = (float*)alloc((size_t)n * 9 * 4);
    __hip_bfloat16* aggx_bf = (__hip_bfloat16*)alloc((size_t)(n + 64) * 32 * 2);
    __hip_bfloat16* W1frag  = (__hip_bfloat16*)alloc((size_t)32 * 64 * 8 * 2);
    __hip_bfloat16* t2 = (__hip_bfloat16*)alloc((size_t)n * 128 * 2);
    float2* t3 = (float2*)alloc((size_t)n * 8);

    const int B = 256;
    int shift = 8;  // packed binned requires shift==8 (dst_local 8b) and n < 2^24
    int nbuck = ((n - 1) >> shift) + 1;
    int chunk = (E + NBLK - 1) / NBLK;

    k_hist<<<NBLK, B, 0, stream>>>(dst, E, chunk, shift, nbuck, histBlk);
    k_scatterbin<<<NBLK, B, 0, stream>>>(src, dst, E, chunk, shift, nbuck, histBlk, binned);
    k_csrbuild<<<nbuck, B, 0, stream>>>(binned, histBlk, x, E, shift, n, nbuck,
                                        row_ptr, dinv, xs, csr);

    int nagg = (n + 7) / 8;                   // 6250 agg1 blocks (+8 W1frag)
    k_agg1w<<<nagg + 8, B, 0, stream>>>(xs, dinv, row_ptr, csr, W1,
                                        aggx_bf, W1frag, n, nagg);

    int ntile = (n + 15) / 16;                // 3125
    int npair = (ntile + 1) / 2;              // 1563 wave-tasks (32 rows each)
    k_l12<<<(npair + 7) / 8, 512, 0, stream>>>(aggx_bf, W1frag, b1, W2, dinv, t2, n, npair);
    k_agg2<<<(n + 3) / 4, 256, 0, stream>>>((const uint*)t2, dinv, row_ptr, csr, b2, W3, t3, n);

    k_agg3<<<(n + B - 1) / B, B, 0, stream>>>(t3, dinv, row_ptr, csr, b3, (float2*)d_out, n);
}

// Round 11
// 185.278 us; speedup vs baseline: 1.0669x; 1.0669x over previous
//
#include <hip/hip_runtime.h>
#include <hip/hip_bf16.h>

typedef __attribute__((ext_vector_type(8))) short short8;
typedef __attribute__((ext_vector_type(4))) float float4v;
typedef unsigned int uint;

#define NBLK 192  // blocks for hist/scatterbin passes

static __device__ __forceinline__ float2 up_bf2(uint v) {
    float2 r;
    r.x = __uint_as_float(v << 16);
    r.y = __uint_as_float(v & 0xffff0000u);
    return r;
}
static __device__ __forceinline__ short f2bf_bits(float x) {
    union { __hip_bfloat16 h; short s; } u;
    u.h = __float2bfloat16(x);
    return u.s;
}

// ---------------- per-(bucket,block) histogram, LDS only ----------------
// r30: int4 edge reads (16 B/lane); chunk is 4-aligned so vector loads are safe.

__global__ __launch_bounds__(256) void k_hist(const int* __restrict__ dst, int E, int chunk,
        int shift, int nbuck, int* __restrict__ histBlk) {
    __shared__ int h[256];
    h[threadIdx.x] = 0;
    __syncthreads();
    int blk = blockIdx.x;
    int e0 = blk * chunk, e1 = min(E, e0 + chunk);
    int nv = (e1 - e0) >> 2;                   // full int4s in [e0, e1)
    const int4* dv = reinterpret_cast<const int4*>(dst + e0);
    for (int i = threadIdx.x; i < nv; i += 256) {
        int4 d = dv[i];
        atomicAdd(&h[d.x >> shift], 1);
        atomicAdd(&h[d.y >> shift], 1);
        atomicAdd(&h[d.z >> shift], 1);
        atomicAdd(&h[d.w >> shift], 1);
    }
    for (int e = e0 + (nv << 2) + threadIdx.x; e < e1; e += 256)  // tail <4
        atomicAdd(&h[dst[e] >> shift], 1);
    __syncthreads();
    if (threadIdx.x < nbuck) histBlk[threadIdx.x * NBLK + blk] = h[threadIdx.x];
}

// ---------------- bucket totals ----------------

__global__ __launch_bounds__(256) void k_btot(const int* __restrict__ histBlk,
                                              int* __restrict__ btot) {
    __shared__ int s[256];
    int b = blockIdx.x, t = threadIdx.x;
    s[t] = (t < NBLK) ? histBlk[b * NBLK + t] : 0;
    __syncthreads();
    for (int off = 128; off; off >>= 1) {
        if (t < off) s[t] += s[t + off];
        __syncthreads();
    }
    if (t == 0) btot[b] = s[0];
}

// ---------------- per-(bucket,block) bases + bucket bases ----------------

__global__ __launch_bounds__(256) void k_bscan(const int* __restrict__ histBlk,
        const int* __restrict__ btot, int nbuck,
        int* __restrict__ baseBlk, int* __restrict__ bucketBase) {
    __shared__ int s[256], sb[256];
    int b = blockIdx.x, t = threadIdx.x;
    int v = (t < NBLK) ? histBlk[b * NBLK + t] : 0;
    s[t] = v;
    sb[t] = (t < nbuck) ? btot[t] : 0;
    __syncthreads();
    for (int off = 1; off < 256; off <<= 1) {
        int u = (t >= off) ? s[t - off] : 0;
        int u2 = (t >= off) ? sb[t - off] : 0;
        __syncthreads();
        s[t] += u;
        sb[t] += u2;
        __syncthreads();
    }
    int base = (b > 0) ? sb[b - 1] : 0;  // exclusive prefix of bucket totals
    if (t < NBLK) baseBlk[b * NBLK + t] = base + s[t] - v;
    if (t == 0) bucketBase[b] = base;
}

// ---------------- scatter into per-(bucket,block) slices, packed payload ----------------
// binned word = src (24b) | dst_local (8b).  Requires n < 2^24 and shift == 8.
// r30: int4 reads of src/dst (16 B/lane).

__global__ __launch_bounds__(256) void k_scatterbin(const int* __restrict__ src,
        const int* __restrict__ dst, int E, int chunk, int shift, int nbuck,
        const int* __restrict__ baseBlk, uint* __restrict__ binned) {
    __shared__ int cur[256];
    int blk = blockIdx.x;
    if (threadIdx.x < nbuck) cur[threadIdx.x] = baseBlk[threadIdx.x * NBLK + blk];
    __syncthreads();
    int e0 = blk * chunk, e1 = min(E, e0 + chunk);
    int mask = (1 << shift) - 1;
    int nv = (e1 - e0) >> 2;
    const int4* dv = reinterpret_cast<const int4*>(dst + e0);
    const int4* sv = reinterpret_cast<const int4*>(src + e0);
    for (int i = threadIdx.x; i < nv; i += 256) {
        int4 d = dv[i];
        int4 s = sv[i];
        int p0 = atomicAdd(&cur[d.x >> shift], 1);
        binned[p0] = (uint)s.x | ((uint)(d.x & mask) << 24);
        int p1 = atomicAdd(&cur[d.y >> shift], 1);
        binned[p1] = (uint)s.y | ((uint)(d.y & mask) << 24);
        int p2 = atomicAdd(&cur[d.z >> shift], 1);
        binned[p2] = (uint)s.z | ((uint)(d.z & mask) << 24);
        int p3 = atomicAdd(&cur[d.w >> shift], 1);
        binned[p3] = (uint)s.w | ((uint)(d.w & mask) << 24);
    }
    for (int e = e0 + (nv << 2) + threadIdx.x; e < e1; e += 256) {  // tail <4
        int d = dst[e];
        int pos = atomicAdd(&cur[d >> shift], 1);
        binned[pos] = (uint)src[e] | ((uint)(d & mask) << 24);
    }
}

// ---------------- per-bucket: counts -> row_ptr/dinv/xs, then exact csr scatter ----------------

__global__ __launch_bounds__(256) void k_csrbuild(const uint* __restrict__ binned,
        const int* __restrict__ bucketBase, const float* __restrict__ x,
        int E, int shift, int n, int nbuck,
        int* __restrict__ row_ptr, float* __restrict__ dinv, float* __restrict__ xs,
        int* __restrict__ csr) {
    __shared__ int cnt[256], lcur[256];
    int b = blockIdx.x, t = threadIdx.x;
    cnt[t] = 0;
    __syncthreads();
    int lo = bucketBase[b];
    int hi = (b + 1 < nbuck) ? bucketBase[b + 1] : E;
    for (int e = lo + t; e < hi; e += 256)
        atomicAdd(&cnt[binned[e] >> 24], 1);
    __syncthreads();
    int c = cnt[t];
    lcur[t] = c;
    __syncthreads();
    for (int off = 1; off < 256; off <<= 1) {
        int u = (t >= off) ? lcur[t - off] : 0;
        __syncthreads();
        lcur[t] += u;
        __syncthreads();
    }
    int node0 = b << shift;
    int nodeEnd = min(n, (b + 1) << shift);
    int cntNodes = nodeEnd - node0;
    int myBase = lo + lcur[t] - c;  // exclusive prefix within bucket
    if (t < cntNodes) {
        row_ptr[node0 + t] = myBase;
        dinv[node0 + t] = rsqrtf((float)(c + 1));  // +1 self-loop
    }
    if (b == nbuck - 1 && t == 0) row_ptr[n] = E;
    for (int j = t; j < cntNodes * 9; j += 256) {
        int nl = j / 9, f = j - nl * 9;
        float dnl = rsqrtf((float)(cnt[nl] + 1));
        xs[(size_t)(node0 + nl) * 9 + f] = dnl * x[(size_t)(node0 + nl) * 9 + f];
    }
    __syncthreads();
    lcur[t] = myBase;  // running cursors
    __syncthreads();
    for (int e = lo + t; e < hi; e += 256) {
        uint p = binned[e];
        int pos = atomicAdd(&lcur[p >> 24], 1);
        csr[pos] = (int)(p & 0xFFFFFF);
    }
}

// ---------------- Layer 1 aggregate v2 (+ fused W1 frag prebuild) ----------------
// r28: 32 lanes/node = 2 edge-slots x 16 features, 8-deep unroll -> 16 edges
// per chunk, 8 gathers in flight per lane.  shfl_xor(16) merges edge slots.

__global__ __launch_bounds__(256) void k_agg1w(const float* __restrict__ xs,
                       const float* __restrict__ dinv,
                       const int* __restrict__ row_ptr, const int* __restrict__ csr,
                       const float* __restrict__ W1,
                       __hip_bfloat16* __restrict__ aggx_bf,
                       __hip_bfloat16* __restrict__ W1frag, int n, int nagg) {
    int bid = blockIdx.x;
    if (bid >= nagg) {  // W1frag role (8 blocks, 2048 threads)
        int t = (bid - nagg) * 256 + threadIdx.x;
        if (t < 32 * 64) {
            int ctile = t >> 6, lane = t & 63;
            int col = ctile * 16 + (lane & 15);
            int k0 = (lane >> 4) * 8;
            short8 o;
#pragma unroll
            for (int j = 0; j < 8; ++j) {
                int k = k0 + j;
                o[j] = f2bf_bits(k < 9 ? W1[k * 512 + col] : 0.f);
            }
            *reinterpret_cast<short8*>(W1frag + (size_t)t * 8) = o;
        }
        return;
    }
    int node = bid * 8 + (threadIdx.x >> 5);
    if (node >= n) return;
    int l = threadIdx.x & 31;
    int slot = l >> 4;        // edge slot 0/1
    int f = l & 15;
    bool act = f < 9;
    float acc = (act && slot == 0) ? xs[node * 9 + f] : 0.f;  // self-loop once
    int e0 = row_ptr[node], e1 = row_ptr[node + 1];
    int e = e0;
    for (; e + 16 <= e1; e += 16) {       // 8 gathers in flight per lane
        int si[8];
        float xv[8];
#pragma unroll
        for (int j = 0; j < 8; ++j) si[j] = csr[e + 2 * j + slot];
#pragma unroll
        for (int j = 0; j < 8; ++j) xv[j] = act ? xs[si[j] * 9 + f] : 0.f;
#pragma unroll
        for (int j = 0; j < 8; ++j) acc += xv[j];
    }
    for (; e + 4 <= e1; e += 4) {         // 2 per slot
        int s0 = csr[e + slot], s1 = csr[e + 2 + slot];
        float x0 = act ? xs[s0 * 9 + f] : 0.f;
        float x1 = act ? xs[s1 * 9 + f] : 0.f;
        acc += x0 + x1;
    }
    for (; e + 2 <= e1; e += 2) {         // 1 per slot
        int s0 = csr[e + slot];
        acc += act ? xs[s0 * 9 + f] : 0.f;
    }
    if (e < e1 && slot == 0) {            // final odd edge
        int s0 = csr[e];
        acc += act ? xs[s0 * 9 + f] : 0.f;
    }
    acc += __shfl_xor(acc, 16);           // merge edge slots
    if (slot == 0) {
        float v = act ? dinv[node] * acc : 0.f;
        __hip_bfloat16* op = aggx_bf + (size_t)node * 32;
        union { __hip_bfloat16 h; short s; } u;
        u.h = __float2bfloat16(v);
        reinterpret_cast<short*>(op)[f] = u.s;
        reinterpret_cast<short*>(op)[16 + f] = 0;
    }
}

// ---------------- Fused layer1-MFMA + layer2 GEMM (r21 best config) ----------------

__global__ __launch_bounds__(512, 2) void k_l12(const __hip_bfloat16* __restrict__ aggx_bf,
                       const __hip_bfloat16* __restrict__ W1frag, const float* __restrict__ b1,
                       const float* __restrict__ W2, const float* __restrict__ dinv,
                       __hip_bfloat16* __restrict__ t2, int n, int npair) {
    __shared__ short bsh[64 * 128 * 8];   // 128 KB: [kb 0..63][c 0..127][j 0..7]
    __shared__ short h1s[8][2][16][40];   // 20 KB: per-wave 2 tiles x 16 rows x 32 cols
    int t = threadIdx.x;

    // Stage all 128 cols of W2 (fp32 -> bf16) into LDS.
    for (int idx = t; idx < 64 * 128; idx += 512) {
        int kb = idx >> 7, c = idx & 127;
        const float* wp = W2 + (size_t)(kb * 8) * 128 + c;
        short8 o;
#pragma unroll
        for (int j = 0; j < 8; ++j) o[j] = f2bf_bits(wp[j * 128]);
        *reinterpret_cast<short8*>(bsh + (size_t)idx * 8) = o;
    }
    __syncthreads();

    int wid = t >> 6, lane = t & 63;
    int pair = blockIdx.x * 8 + wid;
    if (pair >= npair) return;
    int r = lane & 15, quad = lane >> 4;
    short (*hs0)[40] = h1s[wid][0];
    short (*hs1)[40] = h1s[wid][1];

    int m0 = pair << 5;
    short8 aagg0 = *reinterpret_cast<const short8*>(
        aggx_bf + (size_t)(m0 + r) * 32 + quad * 8);
    short8 aagg1 = *reinterpret_cast<const short8*>(
        aggx_bf + (size_t)(m0 + 16 + r) * 32 + quad * 8);

    float4v acc0[8], acc1[8];
#pragma unroll
    for (int cg = 0; cg < 8; ++cg) {
        acc0[cg] = (float4v){0, 0, 0, 0};
        acc1[cg] = (float4v){0, 0, 0, 0};
    }

    for (int kt = 0; kt < 16; ++kt) {
        short8 bf0 = *reinterpret_cast<const short8*>(
            W1frag + ((size_t)(2 * kt) * 64 + lane) * 8);
        short8 bf1 = *reinterpret_cast<const short8*>(
            W1frag + ((size_t)(2 * kt + 1) * 64 + lane) * 8);
        float4v c00 = __builtin_amdgcn_mfma_f32_16x16x32_bf16(
            aagg0, bf0, (float4v){0, 0, 0, 0}, 0, 0, 0);
        float4v c01 = __builtin_amdgcn_mfma_f32_16x16x32_bf16(
            aagg0, bf1, (float4v){0, 0, 0, 0}, 0, 0, 0);
        float4v c10 = __builtin_amdgcn_mfma_f32_16x16x32_bf16(
            aagg1, bf0, (float4v){0, 0, 0, 0}, 0, 0, 0);
        float4v c11 = __builtin_amdgcn_mfma_f32_16x16x32_bf16(
            aagg1, bf1, (float4v){0, 0, 0, 0}, 0, 0, 0);
        float bb0 = b1[kt * 32 + r];
        float bb1 = b1[kt * 32 + 16 + r];
#pragma unroll
        for (int i = 0; i < 4; ++i) {
            int row = quad * 4 + i;
            hs0[row][r]      = f2bf_bits(fmaxf(c00[i] + bb0, 0.f));
            hs0[row][16 + r] = f2bf_bits(fmaxf(c01[i] + bb1, 0.f));
            hs1[row][r]      = f2bf_bits(fmaxf(c10[i] + bb0, 0.f));
            hs1[row][16 + r] = f2bf_bits(fmaxf(c11[i] + bb1, 0.f));
        }
        short8 am0 = *reinterpret_cast<const short8*>(&hs0[r][quad * 8]);
        short8 am1 = *reinterpret_cast<const short8*>(&hs1[r][quad * 8]);
#pragma unroll
        for (int cg = 0; cg < 8; ++cg) {
            short8 b = *reinterpret_cast<const short8*>(
                bsh + (size_t)(((kt * 4 + quad) * 128) + cg * 16 + r) * 8);
            acc0[cg] = __builtin_amdgcn_mfma_f32_16x16x32_bf16(am0, b, acc0[cg], 0, 0, 0);
            acc1[cg] = __builtin_amdgcn_mfma_f32_16x16x32_bf16(am1, b, acc1[cg], 0, 0, 0);
        }
    }

#pragma unroll
    for (int i = 0; i < 4; ++i) {
        int node0 = m0 + quad * 4 + i;
        if (node0 < n) {
            float di = dinv[node0];
            __hip_bfloat16* op = t2 + (size_t)node0 * 128 + r;
#pragma unroll
            for (int cg = 0; cg < 8; ++cg)
                op[cg * 16] = __float2bfloat16(di * acc0[cg][i]);
        }
        int node1 = m0 + 16 + quad * 4 + i;
        if (node1 < n) {
            float di = dinv[node1];
            __hip_bfloat16* op = t2 + (size_t)node1 * 128 + r;
#pragma unroll
            for (int cg = 0; cg < 8; ++cg)
                op[cg * 16] = __float2bfloat16(di * acc1[cg][i]);
        }
    }
}

// ---------------- Layer 2 aggregate + fused layer-3 matmul (r20 proven) ----------------

__global__ __launch_bounds__(256) void k_agg2(const uint* __restrict__ t2u,
                       const float* __restrict__ dinv,
                       const int* __restrict__ row_ptr, const int* __restrict__ csr,
                       const float* __restrict__ b2, const float* __restrict__ W3,
                       float2* __restrict__ t3, int n) {
    int node = blockIdx.x * 4 + (threadIdx.x >> 6);
    if (node >= n) return;
    int lane = threadIdx.x & 63;
    int half = lane >> 5;    // 0: even edges, 1: odd edges
    int cl = lane & 31;      // channel chunk: channels 4*cl .. 4*cl+3
    const uint2* t2v = reinterpret_cast<const uint2*>(t2u);

    float a0 = 0.f, a1 = 0.f, a2 = 0.f, a3 = 0.f;
    if (half == 0) {  // self row (t2' = dinv*t2), added once
        uint2 sv = t2v[(size_t)node * 32 + cl];
        float2 pa = up_bf2(sv.x), pb = up_bf2(sv.y);
        a0 = pa.x; a1 = pa.y; a2 = pb.x; a3 = pb.y;
    }

    int e0 = row_ptr[node], e1 = row_ptr[node + 1];
    int eb = e0;
    for (; eb + 16 <= e1; eb += 16) {  // 8 edges per half in flight
        int si[8];
        uint2 ri[8];
#pragma unroll
        for (int j = 0; j < 8; ++j) si[j] = csr[eb + half + 2 * j];
#pragma unroll
        for (int j = 0; j < 8; ++j) ri[j] = t2v[(size_t)si[j] * 32 + cl];
#pragma unroll
        for (int j = 0; j < 8; ++j) {
            float2 qa = up_bf2(ri[j].x), qb = up_bf2(ri[j].y);
            a0 += qa.x; a1 += qa.y; a2 += qb.x; a3 += qb.y;
        }
    }
    for (; eb + 4 <= e1; eb += 4) {  // 2 edges per half
        int s0 = csr[eb + half], s1 = csr[eb + half + 2];
        uint2 r0 = t2v[(size_t)s0 * 32 + cl];
        uint2 r1 = t2v[(size_t)s1 * 32 + cl];
        float2 qa = up_bf2(r0.x), qb = up_bf2(r0.y);
        float2 qc = up_bf2(r1.x), qd = up_bf2(r1.y);
        a0 += qa.x + qc.x; a1 += qa.y + qc.y;
        a2 += qb.x + qd.x; a3 += qb.y + qd.y;
    }
    for (int e = eb + half; e < e1; e += 2) {  // tail 0-3 edges
        uint2 rv = t2v[(size_t)csr[e] * 32 + cl];
        float2 qa = up_bf2(rv.x), qb = up_bf2(rv.y);
        a0 += qa.x; a1 += qa.y; a2 += qb.x; a3 += qb.y;
    }

    // merge even/odd halves: lanes l and l^32 hold same channel chunk
    a0 += __shfl_xor(a0, 32);
    a1 += __shfl_xor(a1, 32);
    a2 += __shfl_xor(a2, 32);
    a3 += __shfl_xor(a3, 32);

    float di = dinv[node];
    float4 bb = *reinterpret_cast<const float4*>(b2 + 4 * cl);
    float h0 = fmaxf(di * a0 + bb.x, 0.f);
    float h1v = fmaxf(di * a1 + bb.y, 0.f);
    float h2 = fmaxf(di * a2 + bb.z, 0.f);
    float h3 = fmaxf(di * a3 + bb.w, 0.f);
    float4 wlo = *reinterpret_cast<const float4*>(W3 + 8 * cl);      // rows 4cl, 4cl+1
    float4 whi = *reinterpret_cast<const float4*>(W3 + 8 * cl + 4);  // rows 4cl+2, 4cl+3
    float c0 = h0 * wlo.x + h1v * wlo.z + h2 * whi.x + h3 * whi.z;
    float c1 = h0 * wlo.y + h1v * wlo.w + h2 * whi.y + h3 * whi.w;
#pragma unroll
    for (int off = 16; off; off >>= 1) {  // reduce within each 32-lane group
        c0 += __shfl_xor(c0, off);
        c1 += __shfl_xor(c1, off);
    }
    if (lane == 0) t3[node] = make_float2(di * c0, di * c1);  // prescaled
}

// ---------------- Layer 3 aggregate + log_softmax ----------------

__global__ void k_agg3(const float2* __restrict__ t3, const float* __restrict__ dinv,
                       const int* __restrict__ row_ptr, const int* __restrict__ csr,
                       const float* __restrict__ b3, float2* __restrict__ outv, int n) {
    int node = blockIdx.x * blockDim.x + threadIdx.x;
    if (node >= n) return;
    float2 s = t3[node];  // self (t3' = dinv*t3)
    float a0 = s.x, a1 = s.y;
    int e0 = row_ptr[node], e1 = row_ptr[node + 1];
    int e = e0;
    for (; e + 4 <= e1; e += 4) {
        int s0 = csr[e], s1 = csr[e + 1], s2 = csr[e + 2], s3 = csr[e + 3];
        float2 q0 = t3[s0], q1 = t3[s1], q2 = t3[s2], q3 = t3[s3];
        a0 += q0.x + q1.x + q2.x + q3.x;
        a1 += q0.y + q1.y + q2.y + q3.y;
    }
    for (; e < e1; ++e) {
        float2 q0 = t3[csr[e]];
        a0 += q0.x;
        a1 += q0.y;
    }
    float di = dinv[node];
    float z0 = di * a0 + b3[0];
    float z1 = di * a1 + b3[1];
    float m = fmaxf(z0, z1);
    float lse = m + logf(expf(z0 - m) + expf(z1 - m));
    outv[node] = make_float2(z0 - lse, z1 - lse);
}

// ---------------- launch ----------------

extern "C" void kernel_launch(void* const* d_in, const int* in_sizes, int n_in,
                              void* d_out, int out_size, void* d_ws, size_t ws_size,
                              hipStream_t stream) {
    const float* x  = (const float*)d_in[0];
    const float* W1 = (const float*)d_in[1];
    const float* b1 = (const float*)d_in[2];
    const float* W2 = (const float*)d_in[3];
    const float* b2 = (const float*)d_in[4];
    const float* W3 = (const float*)d_in[5];
    const float* b3 = (const float*)d_in[6];
    const int* edges = (const int*)d_in[7];

    int n = in_sizes[0] / 9;
    int E = in_sizes[7] / 2;
    const int* src = edges;
    const int* dst = edges + E;

    char* p = (char*)d_ws;
    auto alloc = [&](size_t bytes) {
        char* q = p;
        p += (bytes + 511) & ~(size_t)511;
        return q;
    };
    float* dinv       = (float*)alloc((size_t)n * 4);
    int*   row_ptr    = (int*)alloc((size_t)(n + 1) * 4);
    int*   csr        = (int*)alloc((size_t)E * 4);
    int*   histBlk    = (int*)alloc((size_t)256 * NBLK * 4);
    int*   baseBlk    = (int*)alloc((size_t)256 * NBLK * 4);
    int*   btot       = (int*)alloc(256 * 4);
    int*   bucketBase = (int*)alloc(256 * 4);
    uint*  binned     = (uint*)alloc((size_t)E * 4);
    float* xs         = (float*)alloc((size_t)n * 9 * 4);
    __hip_bfloat16* aggx_bf = (__hip_bfloat16*)alloc((size_t)(n + 64) * 32 * 2);
    __hip_bfloat16* W1frag  = (__hip_bfloat16*)alloc((size_t)32 * 64 * 8 * 2);
    __hip_bfloat16* t2 = (__hip_bfloat16*)alloc((size_t)n * 128 * 2);
    float2* t3 = (float2*)alloc((size_t)n * 8);

    const int B = 256;
    int shift = 8;  // packed binned requires shift==8 (dst_local 8b) and n < 2^24
    int nbuck = ((n - 1) >> shift) + 1;
    int chunk = ((E + NBLK - 1) / NBLK + 3) & ~3;   // 4-aligned for int4 edge reads

    k_hist<<<NBLK, B, 0, stream>>>(dst, E, chunk, shift, nbuck, histBlk);
    k_btot<<<nbuck, B, 0, stream>>>(histBlk, btot);
    k_bscan<<<nbuck, B, 0, stream>>>(histBlk, btot, nbuck, baseBlk, bucketBase);
    k_scatterbin<<<NBLK, B, 0, stream>>>(src, dst, E, chunk, shift, nbuck, baseBlk, binned);
    k_csrbuild<<<nbuck, B, 0, stream>>>(binned, bucketBase, x, E, shift, n, nbuck,
                                        row_ptr, dinv, xs, csr);

    int nagg = (n + 7) / 8;                   // 6250 agg1 blocks (+8 W1frag)
    k_agg1w<<<nagg + 8, B, 0, stream>>>(xs, dinv, row_ptr, csr, W1,
                                        aggx_bf, W1frag, n, nagg);

    int ntile = (n + 15) / 16;                // 3125
    int npair = (ntile + 1) / 2;              // 1563 wave-tasks (32 rows each)
    k_l12<<<(npair + 7) / 8, 512, 0, stream>>>(aggx_bf, W1frag, b1, W2, dinv, t2, n, npair);
    k_agg2<<<(n + 3) / 4, 256, 0, stream>>>((const uint*)t2, dinv, row_ptr, csr, b2, W3, t3, n);

    k_agg3<<<(n + B - 1) / B, B, 0, stream>>>(t3, dinv, row_ptr, csr, b3, (float2*)d_out, n);
}

// Round 12
// 181.084 us; speedup vs baseline: 1.0916x; 1.0232x over previous
//
#include <hip/hip_runtime.h>
#include <hip/hip_bf16.h>

typedef __attribute__((ext_vector_type(8))) short short8;
typedef __attribute__((ext_vector_type(4))) float float4v;
typedef unsigned int uint;

#define NBLK 192  // blocks for hist/scatterbin passes

static __device__ __forceinline__ float2 up_bf2(uint v) {
    float2 r;
    r.x = __uint_as_float(v << 16);
    r.y = __uint_as_float(v & 0xffff0000u);
    return r;
}
static __device__ __forceinline__ short f2bf_bits(float x) {
    union { __hip_bfloat16 h; short s; } u;
    u.h = __float2bfloat16(x);
    return u.s;
}

// ---------------- per-(bucket,block) histogram, LDS only ----------------
// r30: int4 edge reads (16 B/lane); chunk is 4-aligned so vector loads are safe.

__global__ __launch_bounds__(256) void k_hist(const int* __restrict__ dst, int E, int chunk,
        int shift, int nbuck, int* __restrict__ histBlk) {
    __shared__ int h[256];
    h[threadIdx.x] = 0;
    __syncthreads();
    int blk = blockIdx.x;
    int e0 = blk * chunk, e1 = min(E, e0 + chunk);
    int nv = (e1 - e0) >> 2;                   // full int4s in [e0, e1)
    const int4* dv = reinterpret_cast<const int4*>(dst + e0);
    for (int i = threadIdx.x; i < nv; i += 256) {
        int4 d = dv[i];
        atomicAdd(&h[d.x >> shift], 1);
        atomicAdd(&h[d.y >> shift], 1);
        atomicAdd(&h[d.z >> shift], 1);
        atomicAdd(&h[d.w >> shift], 1);
    }
    for (int e = e0 + (nv << 2) + threadIdx.x; e < e1; e += 256)  // tail <4
        atomicAdd(&h[dst[e] >> shift], 1);
    __syncthreads();
    if (threadIdx.x < nbuck) histBlk[threadIdx.x * NBLK + blk] = h[threadIdx.x];
}

// ---------------- bucket totals ----------------

__global__ __launch_bounds__(256) void k_btot(const int* __restrict__ histBlk,
                                              int* __restrict__ btot) {
    __shared__ int s[256];
    int b = blockIdx.x, t = threadIdx.x;
    s[t] = (t < NBLK) ? histBlk[b * NBLK + t] : 0;
    __syncthreads();
    for (int off = 128; off; off >>= 1) {
        if (t < off) s[t] += s[t + off];
        __syncthreads();
    }
    if (t == 0) btot[b] = s[0];
}

// ---------------- per-(bucket,block) bases + bucket bases ----------------

__global__ __launch_bounds__(256) void k_bscan(const int* __restrict__ histBlk,
        const int* __restrict__ btot, int nbuck,
        int* __restrict__ baseBlk, int* __restrict__ bucketBase) {
    __shared__ int s[256], sb[256];
    int b = blockIdx.x, t = threadIdx.x;
    int v = (t < NBLK) ? histBlk[b * NBLK + t] : 0;
    s[t] = v;
    sb[t] = (t < nbuck) ? btot[t] : 0;
    __syncthreads();
    for (int off = 1; off < 256; off <<= 1) {
        int u = (t >= off) ? s[t - off] : 0;
        int u2 = (t >= off) ? sb[t - off] : 0;
        __syncthreads();
        s[t] += u;
        sb[t] += u2;
        __syncthreads();
    }
    int base = (b > 0) ? sb[b - 1] : 0;  // exclusive prefix of bucket totals
    if (t < NBLK) baseBlk[b * NBLK + t] = base + s[t] - v;
    if (t == 0) bucketBase[b] = base;
}

// ---------------- scatter into per-(bucket,block) slices, packed payload ----------------
// binned word = src (24b) | dst_local (8b).  Requires n < 2^24 and shift == 8.
// r30: int4 reads of src/dst (16 B/lane).

__global__ __launch_bounds__(256) void k_scatterbin(const int* __restrict__ src,
        const int* __restrict__ dst, int E, int chunk, int shift, int nbuck,
        const int* __restrict__ baseBlk, uint* __restrict__ binned) {
    __shared__ int cur[256];
    int blk = blockIdx.x;
    if (threadIdx.x < nbuck) cur[threadIdx.x] = baseBlk[threadIdx.x * NBLK + blk];
    __syncthreads();
    int e0 = blk * chunk, e1 = min(E, e0 + chunk);
    int mask = (1 << shift) - 1;
    int nv = (e1 - e0) >> 2;
    const int4* dv = reinterpret_cast<const int4*>(dst + e0);
    const int4* sv = reinterpret_cast<const int4*>(src + e0);
    for (int i = threadIdx.x; i < nv; i += 256) {
        int4 d = dv[i];
        int4 s = sv[i];
        int p0 = atomicAdd(&cur[d.x >> shift], 1);
        binned[p0] = (uint)s.x | ((uint)(d.x & mask) << 24);
        int p1 = atomicAdd(&cur[d.y >> shift], 1);
        binned[p1] = (uint)s.y | ((uint)(d.y & mask) << 24);
        int p2 = atomicAdd(&cur[d.z >> shift], 1);
        binned[p2] = (uint)s.z | ((uint)(d.z & mask) << 24);
        int p3 = atomicAdd(&cur[d.w >> shift], 1);
        binned[p3] = (uint)s.w | ((uint)(d.w & mask) << 24);
    }
    for (int e = e0 + (nv << 2) + threadIdx.x; e < e1; e += 256) {  // tail <4
        int d = dst[e];
        int pos = atomicAdd(&cur[d >> shift], 1);
        binned[pos] = (uint)src[e] | ((uint)(d & mask) << 24);
    }
}

// ---------------- per-bucket: counts -> row_ptr/dinv/xs16, then exact csr scatter ----------------
// r31: uint4 binned reads in both passes (head/vector/tail; buckets <8 edges
// stay scalar); xs padded to 16 floats/row (cols 9..15 zero) for coalesced
// 64 B gathers in k_agg1w.

__global__ __launch_bounds__(256) void k_csrbuild(const uint* __restrict__ binned,
        const int* __restrict__ bucketBase, const float* __restrict__ x,
        int E, int shift, int n, int nbuck,
        int* __restrict__ row_ptr, float* __restrict__ dinv, float* __restrict__ xs,
        int* __restrict__ csr) {
    __shared__ int cnt[256], lcur[256];
    int b = blockIdx.x, t = threadIdx.x;
    cnt[t] = 0;
    __syncthreads();
    int lo = bucketBase[b];
    int hi = (b + 1 < nbuck) ? bucketBase[b + 1] : E;
    if (hi - lo >= 8) {
        int loA = (lo + 3) & ~3, hiA = hi & ~3;
        for (int e = lo + t; e < loA; e += 256)
            atomicAdd(&cnt[binned[e] >> 24], 1);
        const uint4* bv = reinterpret_cast<const uint4*>(binned + loA);
        int nv = (hiA - loA) >> 2;
        for (int i = t; i < nv; i += 256) {
            uint4 p = bv[i];
            atomicAdd(&cnt[p.x >> 24], 1);
            atomicAdd(&cnt[p.y >> 24], 1);
            atomicAdd(&cnt[p.z >> 24], 1);
            atomicAdd(&cnt[p.w >> 24], 1);
        }
        for (int e = hiA + t; e < hi; e += 256)
            atomicAdd(&cnt[binned[e] >> 24], 1);
    } else {
        for (int e = lo + t; e < hi; e += 256)
            atomicAdd(&cnt[binned[e] >> 24], 1);
    }
    __syncthreads();
    int c = cnt[t];
    lcur[t] = c;
    __syncthreads();
    for (int off = 1; off < 256; off <<= 1) {
        int u = (t >= off) ? lcur[t - off] : 0;
        __syncthreads();
        lcur[t] += u;
        __syncthreads();
    }
    int node0 = b << shift;
    int nodeEnd = min(n, (b + 1) << shift);
    int cntNodes = nodeEnd - node0;
    int myBase = lo + lcur[t] - c;  // exclusive prefix within bucket
    if (t < cntNodes) {
        row_ptr[node0 + t] = myBase;
        dinv[node0 + t] = rsqrtf((float)(c + 1));  // +1 self-loop
    }
    if (b == nbuck - 1 && t == 0) row_ptr[n] = E;
    for (int j = t; j < cntNodes * 16; j += 256) {   // xs16: 16 floats/row, pad 0
        int nl = j >> 4, f = j & 15;
        float dnl = rsqrtf((float)(cnt[nl] + 1));
        float val = (f < 9) ? dnl * x[(size_t)(node0 + nl) * 9 + f] : 0.f;
        xs[(size_t)(node0 + nl) * 16 + f] = val;
    }
    __syncthreads();
    lcur[t] = myBase;  // running cursors
    __syncthreads();
    if (hi - lo >= 8) {
        int loA = (lo + 3) & ~3, hiA = hi & ~3;
        for (int e = lo + t; e < loA; e += 256) {
            uint p = binned[e];
            int pos = atomicAdd(&lcur[p >> 24], 1);
            csr[pos] = (int)(p & 0xFFFFFF);
        }
        const uint4* bv = reinterpret_cast<const uint4*>(binned + loA);
        int nv = (hiA - loA) >> 2;
        for (int i = t; i < nv; i += 256) {
            uint4 p = bv[i];
            int p0 = atomicAdd(&lcur[p.x >> 24], 1);
            csr[p0] = (int)(p.x & 0xFFFFFF);
            int p1 = atomicAdd(&lcur[p.y >> 24], 1);
            csr[p1] = (int)(p.y & 0xFFFFFF);
            int p2 = atomicAdd(&lcur[p.z >> 24], 1);
            csr[p2] = (int)(p.z & 0xFFFFFF);
            int p3 = atomicAdd(&lcur[p.w >> 24], 1);
            csr[p3] = (int)(p.w & 0xFFFFFF);
        }
        for (int e = hiA + t; e < hi; e += 256) {
            uint p = binned[e];
            int pos = atomicAdd(&lcur[p >> 24], 1);
            csr[pos] = (int)(p & 0xFFFFFF);
        }
    } else {
        for (int e = lo + t; e < hi; e += 256) {
            uint p = binned[e];
            int pos = atomicAdd(&lcur[p >> 24], 1);
            csr[pos] = (int)(p & 0xFFFFFF);
        }
    }
}

// ---------------- Layer 1 aggregate v3 (+ fused W1 frag prebuild) ----------------
// r31: xs padded to 16 floats/row -> every gather is an aligned 64 B row with
// all 16 lanes coalesced; act-selects eliminated (pad sums zeros).  r28 MLP
// structure kept: 32 lanes/node = 2 edge-slots x 16 features, 8-deep unroll.

__global__ __launch_bounds__(256) void k_agg1w(const float* __restrict__ xs,
                       const float* __restrict__ dinv,
                       const int* __restrict__ row_ptr, const int* __restrict__ csr,
                       const float* __restrict__ W1,
                       __hip_bfloat16* __restrict__ aggx_bf,
                       __hip_bfloat16* __restrict__ W1frag, int n, int nagg) {
    int bid = blockIdx.x;
    if (bid >= nagg) {  // W1frag role (8 blocks, 2048 threads)
        int t = (bid - nagg) * 256 + threadIdx.x;
        if (t < 32 * 64) {
            int ctile = t >> 6, lane = t & 63;
            int col = ctile * 16 + (lane & 15);
            int k0 = (lane >> 4) * 8;
            short8 o;
#pragma unroll
            for (int j = 0; j < 8; ++j) {
                int k = k0 + j;
                o[j] = f2bf_bits(k < 9 ? W1[k * 512 + col] : 0.f);
            }
            *reinterpret_cast<short8*>(W1frag + (size_t)t * 8) = o;
        }
        return;
    }
    int node = bid * 8 + (threadIdx.x >> 5);
    if (node >= n) return;
    int l = threadIdx.x & 31;
    int slot = l >> 4;        // edge slot 0/1
    int f = l & 15;
    float acc = (slot == 0) ? xs[(size_t)node * 16 + f] : 0.f;  // self-loop once
    int e0 = row_ptr[node], e1 = row_ptr[node + 1];
    int e = e0;
    for (; e + 16 <= e1; e += 16) {       // 8 gathers in flight per lane
        int si[8];
        float xv[8];
#pragma unroll
        for (int j = 0; j < 8; ++j) si[j] = csr[e + 2 * j + slot];
#pragma unroll
        for (int j = 0; j < 8; ++j) xv[j] = xs[(size_t)si[j] * 16 + f];
#pragma unroll
        for (int j = 0; j < 8; ++j) acc += xv[j];
    }
    for (; e + 4 <= e1; e += 4) {         // 2 per slot
        int s0 = csr[e + slot], s1 = csr[e + 2 + slot];
        acc += xs[(size_t)s0 * 16 + f] + xs[(size_t)s1 * 16 + f];
    }
    for (; e + 2 <= e1; e += 2) {         // 1 per slot
        acc += xs[(size_t)csr[e + slot] * 16 + f];
    }
    if (e < e1 && slot == 0) {            // final odd edge
        acc += xs[(size_t)csr[e] * 16 + f];
    }
    acc += __shfl_xor(acc, 16);           // merge edge slots
    if (slot == 0) {
        float v = dinv[node] * acc;       // f>=9: acc==0 -> writes 0
        __hip_bfloat16* op = aggx_bf + (size_t)node * 32;
        union { __hip_bfloat16 h; short s; } u;
        u.h = __float2bfloat16(v);
        reinterpret_cast<short*>(op)[f] = u.s;
        reinterpret_cast<short*>(op)[16 + f] = 0;
    }
}

// ---------------- Fused layer1-MFMA + layer2 GEMM (r21 best config) ----------------

__global__ __launch_bounds__(512, 2) void k_l12(const __hip_bfloat16* __restrict__ aggx_bf,
                       const __hip_bfloat16* __restrict__ W1frag, const float* __restrict__ b1,
                       const float* __restrict__ W2, const float* __restrict__ dinv,
                       __hip_bfloat16* __restrict__ t2, int n, int npair) {
    __shared__ short bsh[64 * 128 * 8];   // 128 KB: [kb 0..63][c 0..127][j 0..7]
    __shared__ short h1s[8][2][16][40];   // 20 KB: per-wave 2 tiles x 16 rows x 32 cols
    int t = threadIdx.x;

    // Stage all 128 cols of W2 (fp32 -> bf16) into LDS.
    for (int idx = t; idx < 64 * 128; idx += 512) {
        int kb = idx >> 7, c = idx & 127;
        const float* wp = W2 + (size_t)(kb * 8) * 128 + c;
        short8 o;
#pragma unroll
        for (int j = 0; j < 8; ++j) o[j] = f2bf_bits(wp[j * 128]);
        *reinterpret_cast<short8*>(bsh + (size_t)idx * 8) = o;
    }
    __syncthreads();

    int wid = t >> 6, lane = t & 63;
    int pair = blockIdx.x * 8 + wid;
    if (pair >= npair) return;
    int r = lane & 15, quad = lane >> 4;
    short (*hs0)[40] = h1s[wid][0];
    short (*hs1)[40] = h1s[wid][1];

    int m0 = pair << 5;
    short8 aagg0 = *reinterpret_cast<const short8*>(
        aggx_bf + (size_t)(m0 + r) * 32 + quad * 8);
    short8 aagg1 = *reinterpret_cast<const short8*>(
        aggx_bf + (size_t)(m0 + 16 + r) * 32 + quad * 8);

    float4v acc0[8], acc1[8];
#pragma unroll
    for (int cg = 0; cg < 8; ++cg) {
        acc0[cg] = (float4v){0, 0, 0, 0};
        acc1[cg] = (float4v){0, 0, 0, 0};
    }

    for (int kt = 0; kt < 16; ++kt) {
        short8 bf0 = *reinterpret_cast<const short8*>(
            W1frag + ((size_t)(2 * kt) * 64 + lane) * 8);
        short8 bf1 = *reinterpret_cast<const short8*>(
            W1frag + ((size_t)(2 * kt + 1) * 64 + lane) * 8);
        float4v c00 = __builtin_amdgcn_mfma_f32_16x16x32_bf16(
            aagg0, bf0, (float4v){0, 0, 0, 0}, 0, 0, 0);
        float4v c01 = __builtin_amdgcn_mfma_f32_16x16x32_bf16(
            aagg0, bf1, (float4v){0, 0, 0, 0}, 0, 0, 0);
        float4v c10 = __builtin_amdgcn_mfma_f32_16x16x32_bf16(
            aagg1, bf0, (float4v){0, 0, 0, 0}, 0, 0, 0);
        float4v c11 = __builtin_amdgcn_mfma_f32_16x16x32_bf16(
            aagg1, bf1, (float4v){0, 0, 0, 0}, 0, 0, 0);
        float bb0 = b1[kt * 32 + r];
        float bb1 = b1[kt * 32 + 16 + r];
#pragma unroll
        for (int i = 0; i < 4; ++i) {
            int row = quad * 4 + i;
            hs0[row][r]      = f2bf_bits(fmaxf(c00[i] + bb0, 0.f));
            hs0[row][16 + r] = f2bf_bits(fmaxf(c01[i] + bb1, 0.f));
            hs1[row][r]      = f2bf_bits(fmaxf(c10[i] + bb0, 0.f));
            hs1[row][16 + r] = f2bf_bits(fmaxf(c11[i] + bb1, 0.f));
        }
        short8 am0 = *reinterpret_cast<const short8*>(&hs0[r][quad * 8]);
        short8 am1 = *reinterpret_cast<const short8*>(&hs1[r][quad * 8]);
#pragma unroll
        for (int cg = 0; cg < 8; ++cg) {
            short8 b = *reinterpret_cast<const short8*>(
                bsh + (size_t)(((kt * 4 + quad) * 128) + cg * 16 + r) * 8);
            acc0[cg] = __builtin_amdgcn_mfma_f32_16x16x32_bf16(am0, b, acc0[cg], 0, 0, 0);
            acc1[cg] = __builtin_amdgcn_mfma_f32_16x16x32_bf16(am1, b, acc1[cg], 0, 0, 0);
        }
    }

#pragma unroll
    for (int i = 0; i < 4; ++i) {
        int node0 = m0 + quad * 4 + i;
        if (node0 < n) {
            float di = dinv[node0];
            __hip_bfloat16* op = t2 + (size_t)node0 * 128 + r;
#pragma unroll
            for (int cg = 0; cg < 8; ++cg)
                op[cg * 16] = __float2bfloat16(di * acc0[cg][i]);
        }
        int node1 = m0 + 16 + quad * 4 + i;
        if (node1 < n) {
            float di = dinv[node1];
            __hip_bfloat16* op = t2 + (size_t)node1 * 128 + r;
#pragma unroll
            for (int cg = 0; cg < 8; ++cg)
                op[cg * 16] = __float2bfloat16(di * acc1[cg][i]);
        }
    }
}

// ---------------- Layer 2 aggregate + fused layer-3 matmul (r20 proven) ----------------

__global__ __launch_bounds__(256) void k_agg2(const uint* __restrict__ t2u,
                       const float* __restrict__ dinv,
                       const int* __restrict__ row_ptr, const int* __restrict__ csr,
                       const float* __restrict__ b2, const float* __restrict__ W3,
                       float2* __restrict__ t3, int n) {
    int node = blockIdx.x * 4 + (threadIdx.x >> 6);
    if (node >= n) return;
    int lane = threadIdx.x & 63;
    int half = lane >> 5;    // 0: even edges, 1: odd edges
    int cl = lane & 31;      // channel chunk: channels 4*cl .. 4*cl+3
    const uint2* t2v = reinterpret_cast<const uint2*>(t2u);

    float a0 = 0.f, a1 = 0.f, a2 = 0.f, a3 = 0.f;
    if (half == 0) {  // self row (t2' = dinv*t2), added once
        uint2 sv = t2v[(size_t)node * 32 + cl];
        float2 pa = up_bf2(sv.x), pb = up_bf2(sv.y);
        a0 = pa.x; a1 = pa.y; a2 = pb.x; a3 = pb.y;
    }

    int e0 = row_ptr[node], e1 = row_ptr[node + 1];
    int eb = e0;
    for (; eb + 16 <= e1; eb += 16) {  // 8 edges per half in flight
        int si[8];
        uint2 ri[8];
#pragma unroll
        for (int j = 0; j < 8; ++j) si[j] = csr[eb + half + 2 * j];
#pragma unroll
        for (int j = 0; j < 8; ++j) ri[j] = t2v[(size_t)si[j] * 32 + cl];
#pragma unroll
        for (int j = 0; j < 8; ++j) {
            float2 qa = up_bf2(ri[j].x), qb = up_bf2(ri[j].y);
            a0 += qa.x; a1 += qa.y; a2 += qb.x; a3 += qb.y;
        }
    }
    for (; eb + 4 <= e1; eb += 4) {  // 2 edges per half
        int s0 = csr[eb + half], s1 = csr[eb + half + 2];
        uint2 r0 = t2v[(size_t)s0 * 32 + cl];
        uint2 r1 = t2v[(size_t)s1 * 32 + cl];
        float2 qa = up_bf2(r0.x), qb = up_bf2(r0.y);
        float2 qc = up_bf2(r1.x), qd = up_bf2(r1.y);
        a0 += qa.x + qc.x; a1 += qa.y + qc.y;
        a2 += qb.x + qd.x; a3 += qb.y + qd.y;
    }
    for (int e = eb + half; e < e1; e += 2) {  // tail 0-3 edges
        uint2 rv = t2v[(size_t)csr[e] * 32 + cl];
        float2 qa = up_bf2(rv.x), qb = up_bf2(rv.y);
        a0 += qa.x; a1 += qa.y; a2 += qb.x; a3 += qb.y;
    }

    // merge even/odd halves: lanes l and l^32 hold same channel chunk
    a0 += __shfl_xor(a0, 32);
    a1 += __shfl_xor(a1, 32);
    a2 += __shfl_xor(a2, 32);
    a3 += __shfl_xor(a3, 32);

    float di = dinv[node];
    float4 bb = *reinterpret_cast<const float4*>(b2 + 4 * cl);
    float h0 = fmaxf(di * a0 + bb.x, 0.f);
    float h1v = fmaxf(di * a1 + bb.y, 0.f);
    float h2 = fmaxf(di * a2 + bb.z, 0.f);
    float h3 = fmaxf(di * a3 + bb.w, 0.f);
    float4 wlo = *reinterpret_cast<const float4*>(W3 + 8 * cl);      // rows 4cl, 4cl+1
    float4 whi = *reinterpret_cast<const float4*>(W3 + 8 * cl + 4);  // rows 4cl+2, 4cl+3
    float c0 = h0 * wlo.x + h1v * wlo.z + h2 * whi.x + h3 * whi.z;
    float c1 = h0 * wlo.y + h1v * wlo.w + h2 * whi.y + h3 * whi.w;
#pragma unroll
    for (int off = 16; off; off >>= 1) {  // reduce within each 32-lane group
        c0 += __shfl_xor(c0, off);
        c1 += __shfl_xor(c1, off);
    }
    if (lane == 0) t3[node] = make_float2(di * c0, di * c1);  // prescaled
}

// ---------------- Layer 3 aggregate + log_softmax ----------------

__global__ void k_agg3(const float2* __restrict__ t3, const float* __restrict__ dinv,
                       const int* __restrict__ row_ptr, const int* __restrict__ csr,
                       const float* __restrict__ b3, float2* __restrict__ outv, int n) {
    int node = blockIdx.x * blockDim.x + threadIdx.x;
    if (node >= n) return;
    float2 s = t3[node];  // self (t3' = dinv*t3)
    float a0 = s.x, a1 = s.y;
    int e0 = row_ptr[node], e1 = row_ptr[node + 1];
    int e = e0;
    for (; e + 4 <= e1; e += 4) {
        int s0 = csr[e], s1 = csr[e + 1], s2 = csr[e + 2], s3 = csr[e + 3];
        float2 q0 = t3[s0], q1 = t3[s1], q2 = t3[s2], q3 = t3[s3];
        a0 += q0.x + q1.x + q2.x + q3.x;
        a1 += q0.y + q1.y + q2.y + q3.y;
    }
    for (; e < e1; ++e) {
        float2 q0 = t3[csr[e]];
        a0 += q0.x;
        a1 += q0.y;
    }
    float di = dinv[node];
    float z0 = di * a0 + b3[0];
    float z1 = di * a1 + b3[1];
    float m = fmaxf(z0, z1);
    float lse = m + logf(expf(z0 - m) + expf(z1 - m));
    outv[node] = make_float2(z0 - lse, z1 - lse);
}

// ---------------- launch ----------------

extern "C" void kernel_launch(void* const* d_in, const int* in_sizes, int n_in,
                              void* d_out, int out_size, void* d_ws, size_t ws_size,
                              hipStream_t stream) {
    const float* x  = (const float*)d_in[0];
    const float* W1 = (const float*)d_in[1];
    const float* b1 = (const float*)d_in[2];
    const float* W2 = (const float*)d_in[3];
    const float* b2 = (const float*)d_in[4];
    const float* W3 = (const float*)d_in[5];
    const float* b3 = (const float*)d_in[6];
    const int* edges = (const int*)d_in[7];

    int n = in_sizes[0] / 9;
    int E = in_sizes[7] / 2;
    const int* src = edges;
    const int* dst = edges + E;

    char* p = (char*)d_ws;
    auto alloc = [&](size_t bytes) {
        char* q = p;
        p += (bytes + 511) & ~(size_t)511;
        return q;
    };
    float* dinv       = (float*)alloc((size_t)n * 4);
    int*   row_ptr    = (int*)alloc((size_t)(n + 1) * 4);
    int*   csr        = (int*)alloc((size_t)E * 4);
    int*   histBlk    = (int*)alloc((size_t)256 * NBLK * 4);
    int*   baseBlk    = (int*)alloc((size_t)256 * NBLK * 4);
    int*   btot       = (int*)alloc(256 * 4);
    int*   bucketBase = (int*)alloc(256 * 4);
    uint*  binned     = (uint*)alloc((size_t)E * 4);
    float* xs         = (float*)alloc((size_t)n * 16 * 4);   // padded to 16 floats/row
    __hip_bfloat16* aggx_bf = (__hip_bfloat16*)alloc((size_t)(n + 64) * 32 * 2);
    __hip_bfloat16* W1frag  = (__hip_bfloat16*)alloc((size_t)32 * 64 * 8 * 2);
    __hip_bfloat16* t2 = (__hip_bfloat16*)alloc((size_t)n * 128 * 2);
    float2* t3 = (float2*)alloc((size_t)n * 8);

    const int B = 256;
    int shift = 8;  // packed binned requires shift==8 (dst_local 8b) and n < 2^24
    int nbuck = ((n - 1) >> shift) + 1;
    int chunk = ((E + NBLK - 1) / NBLK + 3) & ~3;   // 4-aligned for int4 edge reads

    k_hist<<<NBLK, B, 0, stream>>>(dst, E, chunk, shift, nbuck, histBlk);
    k_btot<<<nbuck, B, 0, stream>>>(histBlk, btot);
    k_bscan<<<nbuck, B, 0, stream>>>(histBlk, btot, nbuck, baseBlk, bucketBase);
    k_scatterbin<<<NBLK, B, 0, stream>>>(src, dst, E, chunk, shift, nbuck, baseBlk, binned);
    k_csrbuild<<<nbuck, B, 0, stream>>>(binned, bucketBase, x, E, shift, n, nbuck,
                                        row_ptr, dinv, xs, csr);

    int nagg = (n + 7) / 8;                   // 6250 agg1 blocks (+8 W1frag)
    k_agg1w<<<nagg + 8, B, 0, stream>>>(xs, dinv, row_ptr, csr, W1,
                                        aggx_bf, W1frag, n, nagg);

    int ntile = (n + 15) / 16;                // 3125
    int npair = (ntile + 1) / 2;              // 1563 wave-tasks (32 rows each)
    k_l12<<<(npair + 7) / 8, 512, 0, stream>>>(aggx_bf, W1frag, b1, W2, dinv, t2, n, npair);
    k_agg2<<<(n + 3) / 4, 256, 0, stream>>>((const uint*)t2, dinv, row_ptr, csr, b2, W3, t3, n);

    k_agg3<<<(n + B - 1) / B, B, 0, stream>>>(t3, dinv, row_ptr, csr, b3, (float2*)d_out, n);
}